// Round 10
// baseline (665.236 us; speedup 1.0000x reference)
//
#include <hip/hip_runtime.h>

// Problem dims
#define B_    8
#define N_    1024
#define DIN   512
#define H_    8
#define DH    64
#define DQKV  6144   // 2*DQ + 2*DQ + DV = 512+512+512+512+4096
#define DEXP  2048
#define DTIME 256

typedef __attribute__((ext_vector_type(8))) short s16x8;   // 8 bf16 (MFMA A/B frag)
typedef __attribute__((ext_vector_type(4))) short s16x4;
typedef __attribute__((ext_vector_type(4))) float f32x4;   // MFMA C/D frag

__device__ __forceinline__ unsigned short f2bf(float f) {
  unsigned int u = __float_as_uint(f);
  u = (u + 0x7fffu + ((u >> 16) & 1u)) >> 16;   // RNE
  return (unsigned short)u;
}

__device__ __forceinline__ void gload_lds16(const unsigned short* g, unsigned short* l) {
  __builtin_amdgcn_global_load_lds(
      (const __attribute__((address_space(1))) unsigned int*)(g),
      (__attribute__((address_space(3))) unsigned int*)(l), 16, 0, 0);
}

#define WAITV(n) do { asm volatile("s_waitcnt vmcnt(" #n ")" ::: "memory"); \
                      __builtin_amdgcn_sched_barrier(0); } while (0)
#define WAITL0() do { asm volatile("s_waitcnt lgkmcnt(0)" ::: "memory"); \
                      __builtin_amdgcn_sched_barrier(0); } while (0)

// ---------------- LayerNorm (D=512), optional per-batch additive row, bf16 out ----
__global__ __launch_bounds__(256) void ln_k(
    const float* __restrict__ x, const float* __restrict__ add,
    const float* __restrict__ g, const float* __restrict__ bb,
    unsigned short* __restrict__ out)
{
  int row = blockIdx.x;
  int tid = threadIdx.x;
  const float* xr = x + (size_t)row * DIN;
  float v0 = xr[tid], v1 = xr[tid + 256];
  if (add) {
    const float* ar = add + (size_t)(row >> 10) * DIN;   // row/1024 = batch idx
    v0 += ar[tid]; v1 += ar[tid + 256];
  }
  float s = v0 + v1, sq = v0 * v0 + v1 * v1;
  #pragma unroll
  for (int m = 1; m < 64; m <<= 1) { s += __shfl_xor(s, m, 64); sq += __shfl_xor(sq, m, 64); }
  __shared__ float red[8];
  int w = tid >> 6;
  if ((tid & 63) == 0) { red[w] = s; red[4 + w] = sq; }
  __syncthreads();
  s  = red[0] + red[1] + red[2] + red[3];
  sq = red[4] + red[5] + red[6] + red[7];
  float mean = s * (1.0f / DIN);
  float var  = sq * (1.0f / DIN) - mean * mean;
  float rs = rsqrtf(var + 1e-5f);
  unsigned short* orow = out + (size_t)row * DIN;
  orow[tid]       = f2bf((v0 - mean) * rs * g[tid]       + bb[tid]);
  orow[tid + 256] = f2bf((v1 - mean) * rs * g[tid + 256] + bb[tid + 256]);
}

// ---------------- f32 [R][C] -> bf16 [C][R] transpose (weights) ------------------
__global__ __launch_bounds__(256) void wtrans_k(
    const float* __restrict__ in, unsigned short* __restrict__ out, int R, int C)
{
  __shared__ float tile[32][33];
  int tx = threadIdx.x & 31, ty = threadIdx.x >> 5;
  int c0 = blockIdx.x * 32, r0 = blockIdx.y * 32;
  #pragma unroll
  for (int k = 0; k < 4; ++k)
    tile[ty + k * 8][tx] = in[(size_t)(r0 + ty + k * 8) * C + c0 + tx];
  __syncthreads();
  #pragma unroll
  for (int k = 0; k < 4; ++k)
    out[(size_t)(c0 + ty + k * 8) * R + r0 + tx] = f2bf(tile[tx][ty + k * 8]);
}

// ---------------- time MLP: tp[b][512] = swish(t@Wt1+bt1)@Wt2+bt2 ---------------
__global__ __launch_bounds__(256) void time_k(
    const float* __restrict__ t, const float* __restrict__ Wt1, const float* __restrict__ bt1,
    const float* __restrict__ Wt2, const float* __restrict__ bt2, float* __restrict__ tp)
{
  int b = blockIdx.x, tid = threadIdx.x;
  __shared__ float tl[256], hl[256];
  tl[tid] = t[(size_t)b * 256 + tid];
  __syncthreads();
  float a = bt1[tid];
  for (int k = 0; k < 256; ++k) a += tl[k] * Wt1[(size_t)k * 256 + tid];
  hl[tid] = a / (1.0f + __expf(-a));
  __syncthreads();
  for (int j = tid; j < 512; j += 256) {
    float a2 = bt2[j];
    for (int k = 0; k < 256; ++k) a2 += hl[k] * Wt2[(size_t)k * 512 + j];
    tp[(size_t)b * 512 + j] = a2;
  }
}

// ---------------- bf16 MFMA GEMM: C = epi(A @ Bt^T + bias [+res]) ---------------
// 128x128 tile, BK=32, 4 waves; double-buffered LDS, 1 barrier/k-step.
// Block mapping: column-major tiles grouped per XCD so all m-blocks sharing a
// B-weight tile colocate -> B re-reads become XCD-L2 hits (T1 mechanism).
template<int EPI>
__global__ __launch_bounds__(256) void gemm_bt(
    const unsigned short* __restrict__ A, int lda,
    const unsigned short* __restrict__ Bt,
    const float* __restrict__ bias, const float* __restrict__ res,
    void* __restrict__ C, int ldc, int N, int K,
    unsigned short* __restrict__ vtout)
{
  __shared__ __attribute__((aligned(16))) unsigned short As[2 * 4096];
  __shared__ __attribute__((aligned(16))) unsigned short Bs[2 * 4096];
  int tid = threadIdx.x;
  // XCD-grouped column-major block mapping (grids are multiples of 8)
  int w0 = blockIdx.x + gridDim.x * blockIdx.y;         // hw linear id
  int T = gridDim.x * gridDim.y;
  int per8 = T >> 3;
  int cm = (w0 & 7) * per8 + (w0 >> 3);                 // bijective
  int my = gridDim.y;                                    // m-tiles
  int n_t = cm / my, m_t = cm - n_t * my;
  int m0 = m_t * 128, n0 = n_t * 128;
  int lane = tid & 63, wid = tid >> 6;
  int wr = wid >> 1, wc = wid & 1;
  int lr = lane & 15, lg = lane >> 4, lk = lg * 8;
  f32x4 zero = {0.f, 0.f, 0.f, 0.f};
  f32x4 acc[4][4];
  #pragma unroll
  for (int i = 0; i < 4; ++i)
    #pragma unroll
    for (int j = 0; j < 4; ++j) acc[i][j] = zero;
  int srow = wid * 16 + (lane >> 2);
  int schunk = (lane & 3) * 8;
  const unsigned short* gA0 = A  + (size_t)(m0 + srow) * lda + schunk;
  const unsigned short* gA1 = gA0 + (size_t)64 * lda;
  const unsigned short* gB0 = Bt + (size_t)(n0 + srow) * K + schunk;
  const unsigned short* gB1 = gB0 + (size_t)64 * K;
  int nk = K >> 5;
  gload_lds16(gA0, As + wid * 512);
  gload_lds16(gA1, As + 2048 + wid * 512);
  gload_lds16(gB0, Bs + wid * 512);
  gload_lds16(gB1, Bs + 2048 + wid * 512);
  __syncthreads();
  for (int kq = 0; kq < nk; ++kq) {
    int cur = (kq & 1) * 4096;
    if (kq + 1 < nk) {
      int nxt = ((kq + 1) & 1) * 4096;
      int kt = (kq + 1) * 32;
      gload_lds16(gA0 + kt, As + nxt + wid * 512);
      gload_lds16(gA1 + kt, As + nxt + 2048 + wid * 512);
      gload_lds16(gB0 + kt, Bs + nxt + wid * 512);
      gload_lds16(gB1 + kt, Bs + nxt + 2048 + wid * 512);
    }
    s16x8 af[4], bf[4];
    #pragma unroll
    for (int mf = 0; mf < 4; ++mf)
      af[mf] = *(const s16x8*)&As[cur + (wr * 64 + mf * 16 + lr) * 32 + lk];
    #pragma unroll
    for (int nf = 0; nf < 4; ++nf)
      bf[nf] = *(const s16x8*)&Bs[cur + (wc * 64 + nf * 16 + lr) * 32 + lk];
    #pragma unroll
    for (int mf = 0; mf < 4; ++mf)
      #pragma unroll
      for (int nf = 0; nf < 4; ++nf)
        acc[mf][nf] = __builtin_amdgcn_mfma_f32_16x16x32_bf16(af[mf], bf[nf], acc[mf][nf], 0, 0, 0);
    __syncthreads();
  }
  if (EPI == 3 && n0 >= 2048) {
    #pragma unroll
    for (int mf = 0; mf < 4; ++mf) {
      int row = m0 + wr * 64 + mf * 16 + lg * 4;
      int bb = row >> 10, nn = row & 1023;
      #pragma unroll
      for (int nf = 0; nf < 4; ++nf) {
        int col = n0 + wc * 64 + nf * 16 + lr;
        float bcol = bias[col];
        int hc = col - 2048;
        int hh = hc >> 9, cc = hc & 511;
        unsigned short pk[4];
        #pragma unroll
        for (int r = 0; r < 4; ++r) pk[r] = f2bf(acc[mf][nf][r] + bcol);
        *(s16x4*)(vtout + ((size_t)((bb * 8 + hh) * 512 + cc)) * 1024 + nn) = *(const s16x4*)pk;
      }
    }
    return;
  }
  #pragma unroll
  for (int mf = 0; mf < 4; ++mf)
    #pragma unroll
    for (int nf = 0; nf < 4; ++nf) {
      int col = n0 + wc * 64 + nf * 16 + lr;
      float bcol = bias[col];
      #pragma unroll
      for (int r = 0; r < 4; ++r) {
        int row = m0 + wr * 64 + mf * 16 + lg * 4 + r;
        float v = acc[mf][nf][r] + bcol;
        if (EPI == 1) v = v / (1.0f + __expf(-v));            // swish
        if (EPI == 2) {
          v += res[(size_t)row * N + col];
          ((float*)C)[(size_t)row * ldc + col] = v;
        } else {
          ((unsigned short*)C)[(size_t)row * ldc + col] = f2bf(v);
        }
      }
    }
}

// ---------------- fused differential attention, QBLK=64, counted-vmcnt pipeline -
// (structure unchanged from r9; P stride 68->70 to kill 4-way read conflicts)
__global__ __launch_bounds__(512) void attn_k(
    const unsigned short* __restrict__ qkv, const unsigned short* __restrict__ vt,
    const float* __restrict__ lamp, unsigned short* __restrict__ aout /* = qkv+2048 */)
{
  const float scale = 0.125f;
  __shared__ __attribute__((aligned(16))) unsigned short Kb[2][64 * 128]; // 32KB
  __shared__ __attribute__((aligned(16))) unsigned short Pb[2][64 * 70];  // odd-word stride
  __shared__ float sl[2][64];
  int w0 = blockIdx.x;
  int bx = (w0 & 7) * 128 + (w0 >> 3);        // 1024 blocks, bijective XCD swizzle
  int bh = bx >> 4, qt = bx & 15;
  int b = bh >> 3, h = bh & 7;
  int tid = threadIdx.x;
  int lane = tid & 63, w = tid >> 6;
  int rs = w & 3, kh = w >> 2;
  int lr = lane & 15, lg = lane >> 4, lk = lg * 8;
  int qc1 = h * 64, qc2 = 512 + h * 64, kc1 = 1024 + h * 64, kc2 = 1536 + h * 64;
  f32x4 zero = {0.f, 0.f, 0.f, 0.f};
  const unsigned short* kvbase = qkv + (size_t)(b * N_) * DQKV;

  int srw = lane >> 4;                        // 0..3
  int ci0 = (lane & 15) ^ srw;
  int ci1 = (lane & 15) ^ (4 + srw);
  int scol0 = (ci0 < 8) ? (kc1 + ci0 * 8) : (kc2 + (ci0 - 8) * 8);
  int scol1 = (ci1 < 8) ? (kc1 + ci1 * 8) : (kc2 + (ci1 - 8) * 8);

  s16x8 q1f[2], q2f[2];
  {
    size_t ro = (size_t)(b * N_ + qt * 64 + rs * 16 + lr) * DQKV;
    q1f[0] = *(const s16x8*)(qkv + ro + qc1 + lk);
    q1f[1] = *(const s16x8*)(qkv + ro + qc1 + 32 + lk);
    q2f[0] = *(const s16x8*)(qkv + ro + qc2 + lk);
    q2f[1] = *(const s16x8*)(qkv + ro + qc2 + 32 + lk);
  }

#define STAGE_K(Lb, kt)                                                              \
  do {                                                                               \
    gload_lds16(kvbase + (size_t)((kt) * 64 + w * 8 + srw) * DQKV + scol0,           \
                (Lb) + (w * 8) * 128);                                               \
    gload_lds16(kvbase + (size_t)((kt) * 64 + w * 8 + 4 + srw) * DQKV + scol1,       \
                (Lb) + (w * 8 + 4) * 128);                                           \
  } while (0)

#define KREAD(Lb, row, colu) (*(const s16x8*)&(Lb)[(row) * 128 + ((colu) ^ (((row) & 7) * 8))])

  // ---------------- pass 1: l (sum of exp) for (rows rs*16.., type kh) ----------
  {
    s16x8 qa = kh ? q2f[0] : q1f[0];
    s16x8 qb = kh ? q2f[1] : q1f[1];
    int tco = kh ? 64 : 0;
    float lp[4] = {0.f, 0.f, 0.f, 0.f};
    STAGE_K(Kb[0], 0);
    for (int kt = 0; kt < 16; ++kt) {
      STAGE_K(Kb[(kt + 1) & 1], (kt + 1) & 15);
      WAITV(2);                        // Kst(kt) complete; Kst(kt+1) in flight
      unsigned short* Lb = Kb[kt & 1];
      f32x4 s[4];
      #pragma unroll
      for (int nf = 0; nf < 4; ++nf) {
        int row = nf * 16 + lr;
        s16x8 kb0 = KREAD(Lb, row, tco + lk);
        s16x8 kb1 = KREAD(Lb, row, tco + 32 + lk);
        f32x4 acc = __builtin_amdgcn_mfma_f32_16x16x32_bf16(qa, kb0, zero, 0, 0, 0);
        s[nf] = __builtin_amdgcn_mfma_f32_16x16x32_bf16(qb, kb1, acc, 0, 0, 0);
      }
      #pragma unroll
      for (int nf = 0; nf < 4; ++nf)
        #pragma unroll
        for (int r = 0; r < 4; ++r)
          lp[r] += __expf(s[nf][r] * scale);
      WAITL0();                        // LDS reads landed; loads stay in flight
      __builtin_amdgcn_s_barrier();
    }
    #pragma unroll
    for (int r = 0; r < 4; ++r)
      #pragma unroll
      for (int d = 1; d < 16; d <<= 1) lp[r] += __shfl_xor(lp[r], d, 64);
    if (lr == 0)
      #pragma unroll
      for (int r = 0; r < 4; ++r) sl[kh][rs * 16 + lg * 4 + r] = lp[r];
    __syncthreads();
  }

  float lam = *lamp;
  float r1v[4], r2v[4];
  #pragma unroll
  for (int r = 0; r < 4; ++r) {
    int row = rs * 16 + lg * 4 + r;
    r1v[r] = 1.f / sl[0][row];
    r2v[r] = lam / sl[1][row];
  }

  // ---------------- pass 2: P tiles + PV (Kb[0] pre-warmed with tile 0) ---------
  f32x4 O[4][4];
  #pragma unroll
  for (int mf = 0; mf < 4; ++mf)
    #pragma unroll
    for (int nf = 0; nf < 4; ++nf) O[mf][nf] = zero;
  for (int kt = 0; kt < 16; ++kt) {
    unsigned short* Pt = Pb[kt & 1];
    s16x8 vf[4][2];
    #pragma unroll
    for (int nf = 0; nf < 4; ++nf)
      #pragma unroll
      for (int kq = 0; kq < 2; ++kq)
        vf[nf][kq] = *(const s16x8*)(vt + (size_t)(bh * 512 + w * 64 + nf * 16 + lr) * N_
                                     + kt * 64 + kq * 32 + lk);
    if (kt < 15) STAGE_K(Kb[(kt + 1) & 1], kt + 1);
    WAITV(8);                          // Kst(kt) complete; V + Kst(kt+1) in flight
    unsigned short* Lb = Kb[kt & 1];
    f32x4 s1[2], s2[2];
    #pragma unroll
    for (int nf = 0; nf < 2; ++nf) {
      int row = kh * 32 + nf * 16 + lr;
      s16x8 a0 = KREAD(Lb, row, lk);
      s16x8 a1 = KREAD(Lb, row, 32 + lk);
      s16x8 b0 = KREAD(Lb, row, 64 + lk);
      s16x8 b1 = KREAD(Lb, row, 96 + lk);
      f32x4 t1 = __builtin_amdgcn_mfma_f32_16x16x32_bf16(q1f[0], a0, zero, 0, 0, 0);
      s1[nf]   = __builtin_amdgcn_mfma_f32_16x16x32_bf16(q1f[1], a1, t1, 0, 0, 0);
      f32x4 t2 = __builtin_amdgcn_mfma_f32_16x16x32_bf16(q2f[0], b0, zero, 0, 0, 0);
      s2[nf]   = __builtin_amdgcn_mfma_f32_16x16x32_bf16(q2f[1], b1, t2, 0, 0, 0);
    }
    #pragma unroll
    for (int nf = 0; nf < 2; ++nf)
      #pragma unroll
      for (int r = 0; r < 4; ++r) {
        float p = __expf(s1[nf][r] * scale) * r1v[r]
                - __expf(s2[nf][r] * scale) * r2v[r];
        Pt[(rs * 16 + lg * 4 + r) * 70 + kh * 32 + nf * 16 + lr] = f2bf(p);
      }
    WAITL0();                          // P writes visible; global loads in flight
    __builtin_amdgcn_s_barrier();      // ONE barrier per iteration
    __builtin_amdgcn_s_setprio(1);
    #pragma unroll
    for (int mf = 0; mf < 4; ++mf) {
      s16x8 pf0 = *(const s16x8*)&Pt[(mf * 16 + lr) * 70 + lk];
      s16x8 pf1 = *(const s16x8*)&Pt[(mf * 16 + lr) * 70 + 32 + lk];
      #pragma unroll
      for (int nf = 0; nf < 4; ++nf) {
        O[mf][nf] = __builtin_amdgcn_mfma_f32_16x16x32_bf16(pf0, vf[nf][0], O[mf][nf], 0, 0, 0);
        O[mf][nf] = __builtin_amdgcn_mfma_f32_16x16x32_bf16(pf1, vf[nf][1], O[mf][nf], 0, 0, 0);
      }
    }
    __builtin_amdgcn_s_setprio(0);
  }
#undef STAGE_K
#undef KREAD
  // epilogue
  #pragma unroll
  for (int mf = 0; mf < 4; ++mf)
    #pragma unroll
    for (int nf = 0; nf < 4; ++nf) {
      int col = h * 512 + w * 64 + nf * 16 + lr;
      #pragma unroll
      for (int r = 0; r < 4; ++r) {
        int row = b * N_ + qt * 64 + mf * 16 + lg * 4 + r;
        aout[(size_t)row * DQKV + col] = f2bf(O[mf][nf][r]);
      }
    }
}

// ---------------------------------- launcher ------------------------------------
extern "C" void kernel_launch(void* const* d_in, const int* in_sizes, int n_in,
                              void* d_out, int out_size, void* d_ws, size_t ws_size,
                              hipStream_t stream) {
  const float* x    = (const float*)d_in[0];
  const float* t    = (const float*)d_in[1];
  const float* ln1g = (const float*)d_in[2];
  const float* ln1b = (const float*)d_in[3];
  const float* Wqkv = (const float*)d_in[4];
  const float* bqkv = (const float*)d_in[5];
  const float* lam  = (const float*)d_in[6];
  const float* Wm   = (const float*)d_in[7];
  const float* bm   = (const float*)d_in[8];
  const float* Wt1  = (const float*)d_in[9];
  const float* bt1  = (const float*)d_in[10];
  const float* Wt2  = (const float*)d_in[11];
  const float* bt2  = (const float*)d_in[12];
  const float* lnfg = (const float*)d_in[13];
  const float* lnfb = (const float*)d_in[14];
  const float* Wf1  = (const float*)d_in[15];
  const float* bf1  = (const float*)d_in[16];
  const float* Wf2  = (const float*)d_in[17];
  const float* bf2  = (const float*)d_in[18];
  float* out = (float*)d_out;
  char* ws = (char*)d_ws;

  // workspace layout (bytes), ~209 MB total
  unsigned short* qkv   = (unsigned short*)(ws);                  // [8192][6144] bf16 (100.7MB)
  unsigned short* vt    = (unsigned short*)(ws + 100663296ull);   // [64][512][1024] bf16 (67MB)
  float*          x2    = (float*)(ws + 167772160ull);            // [8192][512] f32 (16.8MB)
  unsigned short* xn    = (unsigned short*)(ws + 184549376ull);   // [8192][512] bf16 (xn, then h)
  unsigned short* WqkvT = (unsigned short*)(ws + 193986560ull);   // [6144][512]
  unsigned short* WmT   = (unsigned short*)(ws + 200278016ull);   // [512][4096]
  unsigned short* Wf1T  = (unsigned short*)(ws + 204472320ull);   // [2048][512]
  unsigned short* Wf2T  = (unsigned short*)(ws + 206569472ull);   // [512][2048]
  float*          tp    = (float*)(ws + 208666624ull);            // [8][512]
  unsigned short* ff1s  = qkv;          // alias: qkv dead after attention
  unsigned short* aout  = qkv + 2048;   // alias: attention out over dead V region

  // weights -> bf16 transposed [N][K]
  wtrans_k<<<dim3(DQKV / 32, DIN / 32),  256, 0, stream>>>(Wqkv, WqkvT, DIN, DQKV);
  wtrans_k<<<dim3(DIN / 32, 4096 / 32),  256, 0, stream>>>(Wm,   WmT,   4096, DIN);
  wtrans_k<<<dim3(DEXP / 32, DIN / 32),  256, 0, stream>>>(Wf1,  Wf1T,  DIN, DEXP);
  wtrans_k<<<dim3(DIN / 32, DEXP / 32),  256, 0, stream>>>(Wf2,  Wf2T,  DEXP, DIN);
  // ln1 + time MLP
  ln_k<<<8192, 256, 0, stream>>>(x, nullptr, ln1g, ln1b, xn);
  time_k<<<8, 256, 0, stream>>>(t, Wt1, bt1, Wt2, bt2, tp);
  // qkv GEMM (V columns written directly transposed into vt)
  gemm_bt<3><<<dim3(DQKV / 128, 8192 / 128), 256, 0, stream>>>(
      xn, DIN, WqkvT, bqkv, nullptr, qkv, DQKV, DQKV, DIN, vt);
  // fused two-pass differential attention (QBLK=64, counted-vmcnt pipeline)
  attn_k<<<1024, 512, 0, stream>>>(qkv, vt, lam, aout);
  // x2 = x + attn_out @ Wm + bm
  gemm_bt<2><<<dim3(DIN / 128, 8192 / 128), 256, 0, stream>>>(
      aout, DQKV, WmT, bm, x, x2, DIN, DIN, 4096, nullptr);
  // h = LN(x2 + tp)
  ln_k<<<8192, 256, 0, stream>>>(x2, tp, lnfg, lnfb, xn);
  // ff1 = swish(h @ Wf1 + bf1)
  gemm_bt<1><<<dim3(DEXP / 128, 8192 / 128), 256, 0, stream>>>(
      xn, DIN, Wf1T, bf1, nullptr, ff1s, DEXP, DEXP, DIN, nullptr);
  // out = x2 + ff1 @ Wf2 + bf2
  gemm_bt<2><<<dim3(DIN / 128, 8192 / 128), 256, 0, stream>>>(
      ff1s, DEXP, Wf2T, bf2, x2, out, DIN, DIN, DEXP, nullptr);
}

// Round 13
// 648.249 us; speedup vs baseline: 1.0262x; 1.0262x over previous
//
#include <hip/hip_runtime.h>

// Problem dims
#define B_    8
#define N_    1024
#define DIN   512
#define H_    8
#define DH    64
#define DQKV  6144   // 2*DQ + 2*DQ + DV = 512+512+512+512+4096
#define DEXP  2048
#define DTIME 256

typedef __attribute__((ext_vector_type(8))) short s16x8;   // 8 bf16 (MFMA A/B frag)
typedef __attribute__((ext_vector_type(4))) short s16x4;
typedef __attribute__((ext_vector_type(4))) float f32x4;   // MFMA C/D frag

__device__ __forceinline__ unsigned short f2bf(float f) {
  unsigned int u = __float_as_uint(f);
  u = (u + 0x7fffu + ((u >> 16) & 1u)) >> 16;   // RNE
  return (unsigned short)u;
}

__device__ __forceinline__ void gload_lds16(const unsigned short* g, unsigned short* l) {
  __builtin_amdgcn_global_load_lds(
      (const __attribute__((address_space(1))) unsigned int*)(g),
      (__attribute__((address_space(3))) unsigned int*)(l), 16, 0, 0);
}

#define WAITV(n) do { asm volatile("s_waitcnt vmcnt(" #n ")" ::: "memory"); \
                      __builtin_amdgcn_sched_barrier(0); } while (0)
#define WAITL0() do { asm volatile("s_waitcnt lgkmcnt(0)" ::: "memory"); \
                      __builtin_amdgcn_sched_barrier(0); } while (0)

// ---------------- LayerNorm (D=512), optional per-batch additive row, bf16 out ----
__global__ __launch_bounds__(256) void ln_k(
    const float* __restrict__ x, const float* __restrict__ add,
    const float* __restrict__ g, const float* __restrict__ bb,
    unsigned short* __restrict__ out)
{
  int row = blockIdx.x;
  int tid = threadIdx.x;
  const float* xr = x + (size_t)row * DIN;
  float v0 = xr[tid], v1 = xr[tid + 256];
  if (add) {
    const float* ar = add + (size_t)(row >> 10) * DIN;   // row/1024 = batch idx
    v0 += ar[tid]; v1 += ar[tid + 256];
  }
  float s = v0 + v1, sq = v0 * v0 + v1 * v1;
  #pragma unroll
  for (int m = 1; m < 64; m <<= 1) { s += __shfl_xor(s, m, 64); sq += __shfl_xor(sq, m, 64); }
  __shared__ float red[8];
  int w = tid >> 6;
  if ((tid & 63) == 0) { red[w] = s; red[4 + w] = sq; }
  __syncthreads();
  s  = red[0] + red[1] + red[2] + red[3];
  sq = red[4] + red[5] + red[6] + red[7];
  float mean = s * (1.0f / DIN);
  float var  = sq * (1.0f / DIN) - mean * mean;
  float rs = rsqrtf(var + 1e-5f);
  unsigned short* orow = out + (size_t)row * DIN;
  orow[tid]       = f2bf((v0 - mean) * rs * g[tid]       + bb[tid]);
  orow[tid + 256] = f2bf((v1 - mean) * rs * g[tid + 256] + bb[tid + 256]);
}

// ---------------- f32 [R][C] -> bf16 [C][R] transpose (weights) ------------------
__global__ __launch_bounds__(256) void wtrans_k(
    const float* __restrict__ in, unsigned short* __restrict__ out, int R, int C)
{
  __shared__ float tile[32][33];
  int tx = threadIdx.x & 31, ty = threadIdx.x >> 5;
  int c0 = blockIdx.x * 32, r0 = blockIdx.y * 32;
  #pragma unroll
  for (int k = 0; k < 4; ++k)
    tile[ty + k * 8][tx] = in[(size_t)(r0 + ty + k * 8) * C + c0 + tx];
  __syncthreads();
  #pragma unroll
  for (int k = 0; k < 4; ++k)
    out[(size_t)(c0 + ty + k * 8) * R + r0 + tx] = f2bf(tile[tx][ty + k * 8]);
}

// ---------------- time MLP: tp[b][512] = swish(t@Wt1+bt1)@Wt2+bt2 ---------------
__global__ __launch_bounds__(256) void time_k(
    const float* __restrict__ t, const float* __restrict__ Wt1, const float* __restrict__ bt1,
    const float* __restrict__ Wt2, const float* __restrict__ bt2, float* __restrict__ tp)
{
  int b = blockIdx.x, tid = threadIdx.x;
  __shared__ float tl[256], hl[256];
  tl[tid] = t[(size_t)b * 256 + tid];
  __syncthreads();
  float a = bt1[tid];
  for (int k = 0; k < 256; ++k) a += tl[k] * Wt1[(size_t)k * 256 + tid];
  hl[tid] = a / (1.0f + __expf(-a));
  __syncthreads();
  for (int j = tid; j < 512; j += 256) {
    float a2 = bt2[j];
    for (int k = 0; k < 256; ++k) a2 += hl[k] * Wt2[(size_t)k * 512 + j];
    tp[(size_t)b * 512 + j] = a2;
  }
}

// ---------------- bf16 MFMA GEMM: C = epi(A @ Bt^T + bias [+res]) ---------------
// 128x128 tile, BK=32, 4 waves; double-buffered LDS, 1 barrier/k-step (r9 config).
template<int EPI>
__global__ __launch_bounds__(256) void gemm_bt(
    const unsigned short* __restrict__ A, int lda,
    const unsigned short* __restrict__ Bt,
    const float* __restrict__ bias, const float* __restrict__ res,
    void* __restrict__ C, int ldc, int N, int K,
    unsigned short* __restrict__ vtout)
{
  __shared__ __attribute__((aligned(16))) unsigned short As[2 * 4096];
  __shared__ __attribute__((aligned(16))) unsigned short Bs[2 * 4096];
  int tid = threadIdx.x;
  int m0 = blockIdx.y * 128, n0 = blockIdx.x * 128;
  int lane = tid & 63, wid = tid >> 6;
  int wr = wid >> 1, wc = wid & 1;
  int lr = lane & 15, lg = lane >> 4, lk = lg * 8;
  f32x4 zero = {0.f, 0.f, 0.f, 0.f};
  f32x4 acc[4][4];
  #pragma unroll
  for (int i = 0; i < 4; ++i)
    #pragma unroll
    for (int j = 0; j < 4; ++j) acc[i][j] = zero;
  int srow = wid * 16 + (lane >> 2);
  int schunk = (lane & 3) * 8;
  const unsigned short* gA0 = A  + (size_t)(m0 + srow) * lda + schunk;
  const unsigned short* gA1 = gA0 + (size_t)64 * lda;
  const unsigned short* gB0 = Bt + (size_t)(n0 + srow) * K + schunk;
  const unsigned short* gB1 = gB0 + (size_t)64 * K;
  int nk = K >> 5;
  gload_lds16(gA0, As + wid * 512);
  gload_lds16(gA1, As + 2048 + wid * 512);
  gload_lds16(gB0, Bs + wid * 512);
  gload_lds16(gB1, Bs + 2048 + wid * 512);
  __syncthreads();
  for (int kq = 0; kq < nk; ++kq) {
    int cur = (kq & 1) * 4096;
    if (kq + 1 < nk) {
      int nxt = ((kq + 1) & 1) * 4096;
      int kt = (kq + 1) * 32;
      gload_lds16(gA0 + kt, As + nxt + wid * 512);
      gload_lds16(gA1 + kt, As + nxt + 2048 + wid * 512);
      gload_lds16(gB0 + kt, Bs + nxt + wid * 512);
      gload_lds16(gB1 + kt, Bs + nxt + 2048 + wid * 512);
    }
    s16x8 af[4], bf[4];
    #pragma unroll
    for (int mf = 0; mf < 4; ++mf)
      af[mf] = *(const s16x8*)&As[cur + (wr * 64 + mf * 16 + lr) * 32 + lk];
    #pragma unroll
    for (int nf = 0; nf < 4; ++nf)
      bf[nf] = *(const s16x8*)&Bs[cur + (wc * 64 + nf * 16 + lr) * 32 + lk];
    #pragma unroll
    for (int mf = 0; mf < 4; ++mf)
      #pragma unroll
      for (int nf = 0; nf < 4; ++nf)
        acc[mf][nf] = __builtin_amdgcn_mfma_f32_16x16x32_bf16(af[mf], bf[nf], acc[mf][nf], 0, 0, 0);
    __syncthreads();
  }
  if (EPI == 3 && n0 >= 2048) {
    #pragma unroll
    for (int mf = 0; mf < 4; ++mf) {
      int row = m0 + wr * 64 + mf * 16 + lg * 4;
      int bb = row >> 10, nn = row & 1023;
      #pragma unroll
      for (int nf = 0; nf < 4; ++nf) {
        int col = n0 + wc * 64 + nf * 16 + lr;
        float bcol = bias[col];
        int hc = col - 2048;
        int hh = hc >> 9, cc = hc & 511;
        unsigned short pk[4];
        #pragma unroll
        for (int r = 0; r < 4; ++r) pk[r] = f2bf(acc[mf][nf][r] + bcol);
        *(s16x4*)(vtout + ((size_t)((bb * 8 + hh) * 512 + cc)) * 1024 + nn) = *(const s16x4*)pk;
      }
    }
    return;
  }
  #pragma unroll
  for (int mf = 0; mf < 4; ++mf)
    #pragma unroll
    for (int nf = 0; nf < 4; ++nf) {
      int col = n0 + wc * 64 + nf * 16 + lr;
      float bcol = bias[col];
      #pragma unroll
      for (int r = 0; r < 4; ++r) {
        int row = m0 + wr * 64 + mf * 16 + lg * 4 + r;
        float v = acc[mf][nf][r] + bcol;
        if (EPI == 1) v = v / (1.0f + __expf(-v));            // swish
        if (EPI == 2) {
          v += res[(size_t)row * N + col];
          ((float*)C)[(size_t)row * ldc + col] = v;
        } else {
          ((unsigned short*)C)[(size_t)row * ldc + col] = f2bf(v);
        }
      }
    }
}

// ---------------- fused differential attention, QBLK=64, fully-pipelined --------
// 8 waves: rs=w&3 (16-row q-stripe), kh=w>>2 (kv-16-half of each 32-kv tile).
// K: per-wave REGISTER prefetch (depth 1, counted vmcnt) - no cross-wave LDS race.
// V: per-wave-PRIVATE LDS slices (64ch x 32kv), TRIPLE-buffered via global_load_lds
//    with a ~2-iteration in-flight window - V latency fully hidden, no races.
// P: [64][36] dbuf in LDS, one lgkm-only barrier per iteration (only x-wave dep).
// pass1 (sum-exp stats) is barrier-free: waves fully independent.
__global__ __launch_bounds__(512) void attn_k(
    const unsigned short* __restrict__ qkv, const unsigned short* __restrict__ vt,
    const float* __restrict__ lamp, unsigned short* __restrict__ aout /* = qkv+2048 */)
{
  const float scale = 0.125f;
  __shared__ __attribute__((aligned(16))) unsigned short V3[3][512 * 32]; // 96KB
  __shared__ __attribute__((aligned(16))) unsigned short Pb[2][64 * 36];  // 9KB
  __shared__ float sl[2][64];
  int w0 = blockIdx.x;
  int bx = (w0 & 7) * 128 + (w0 >> 3);        // 1024 blocks, bijective XCD swizzle
  int bh = bx >> 4, qt = bx & 15;
  int b = bh >> 3, h = bh & 7;
  int tid = threadIdx.x;
  int lane = tid & 63, w = tid >> 6;
  int rs = w & 3, kh = w >> 2;
  int lr = lane & 15, lg = lane >> 4, lk = lg * 8;
  int qc1 = h * 64, qc2 = 512 + h * 64, kc1 = 1024 + h * 64, kc2 = 1536 + h * 64;
  f32x4 zero = {0.f, 0.f, 0.f, 0.f};

  // Q fragments (both types) for rows qt*64 + rs*16 + lr
  s16x8 q1f[2], q2f[2];
  {
    size_t ro = (size_t)(b * N_ + qt * 64 + rs * 16 + lr) * DQKV;
    q1f[0] = *(const s16x8*)(qkv + ro + qc1 + lk);
    q1f[1] = *(const s16x8*)(qkv + ro + qc1 + 32 + lk);
    q2f[0] = *(const s16x8*)(qkv + ro + qc2 + lk);
    q2f[1] = *(const s16x8*)(qkv + ro + qc2 + 32 + lk);
  }

  // ---------------- pass 1: l = sum(exp(S)) for (rows rs*16.., type kh) ---------
  // barrier-free; K via per-wave register prefetch, KVBLK=32, 32 iters.
  {
    int kc = kh ? kc2 : kc1;
    s16x8 qa = kh ? q2f[0] : q1f[0];
    s16x8 qb = kh ? q2f[1] : q1f[1];
    float lp[4] = {0.f, 0.f, 0.f, 0.f};
    s16x8 kcur[2][2], knxt[2][2];
    #pragma unroll
    for (int nf = 0; nf < 2; ++nf) {
      size_t kro = (size_t)(b * N_ + nf * 16 + lr) * DQKV + kc;
      kcur[nf][0] = *(const s16x8*)(qkv + kro + lk);
      kcur[nf][1] = *(const s16x8*)(qkv + kro + 32 + lk);
    }
    for (int kt = 0; kt < 32; ++kt) {
      if (kt < 31) {
        #pragma unroll
        for (int nf = 0; nf < 2; ++nf) {
          size_t kro = (size_t)(b * N_ + (kt + 1) * 32 + nf * 16 + lr) * DQKV + kc;
          knxt[nf][0] = *(const s16x8*)(qkv + kro + lk);
          knxt[nf][1] = *(const s16x8*)(qkv + kro + 32 + lk);
        }
        WAITV(4);
      } else {
        WAITV(0);
      }
      f32x4 s[2];
      #pragma unroll
      for (int nf = 0; nf < 2; ++nf) {
        f32x4 t0 = __builtin_amdgcn_mfma_f32_16x16x32_bf16(qa, kcur[nf][0], zero, 0, 0, 0);
        s[nf] = __builtin_amdgcn_mfma_f32_16x16x32_bf16(qb, kcur[nf][1], t0, 0, 0, 0);
      }
      #pragma unroll
      for (int nf = 0; nf < 2; ++nf)
        #pragma unroll
        for (int r = 0; r < 4; ++r)
          lp[r] += __expf(s[nf][r] * scale);
      if (kt < 31) {
        #pragma unroll
        for (int nf = 0; nf < 2; ++nf) { kcur[nf][0] = knxt[nf][0]; kcur[nf][1] = knxt[nf][1]; }
      }
    }
    #pragma unroll
    for (int r = 0; r < 4; ++r)
      #pragma unroll
      for (int d = 1; d < 16; d <<= 1) lp[r] += __shfl_xor(lp[r], d, 64);
    if (lr == 0)
      #pragma unroll
      for (int r = 0; r < 4; ++r) sl[kh][rs * 16 + lg * 4 + r] = lp[r];
    __syncthreads();
  }

  // normalizers for this lane's q-rows
  float lam = *lamp;
  float r1v[4], r2v[4];
  #pragma unroll
  for (int r = 0; r < 4; ++r) {
    int row = rs * 16 + lg * 4 + r;
    r1v[r] = 1.f / sl[0][row];
    r2v[r] = lam / sl[1][row];
  }

  // V staging: wave-private slice [w*64 .. w*64+64) channels x 32 kv, linear dest;
  // source kv-chunk pre-swizzled: chunk = (lane&3) ^ ((lane>>3)&3)  (rule 21)
  auto stage_v = [&](unsigned short* buf, int kt) {
    int chnk = (lane & 3) ^ ((lane >> 3) & 3);
    #pragma unroll
    for (int i = 0; i < 4; ++i) {
      int ch = w * 64 + i * 16 + (lane >> 2);
      gload_lds16(vt + (size_t)(bh * 512 + ch) * N_ + kt * 32 + chnk * 8,
                  buf + (w * 64 + i * 16) * 32);
    }
  };
#define VREAD(vb, nf) \
  (*(const s16x8*)&(vb)[(w * 64 + (nf) * 16 + lr) * 32 + ((lg ^ ((lr >> 1) & 3)) * 8)])

  // ---------------- pass 2: P tiles + PV, KVBLK=32, 32 iters --------------------
  f32x4 O[4][4];
  #pragma unroll
  for (int mf = 0; mf < 4; ++mf)
    #pragma unroll
    for (int nf = 0; nf < 4; ++nf) O[mf][nf] = zero;

  // prologue: V(0), V(1) staged; K(0) regs
  stage_v(V3[0], 0);
  stage_v(V3[1], 1);
  s16x8 kcur[4], knxt[4];
  {
    size_t kro = (size_t)(b * N_ + kh * 16 + lr) * DQKV;
    kcur[0] = *(const s16x8*)(qkv + kro + kc1 + lk);
    kcur[1] = *(const s16x8*)(qkv + kro + kc1 + 32 + lk);
    kcur[2] = *(const s16x8*)(qkv + kro + kc2 + lk);
    kcur[3] = *(const s16x8*)(qkv + kro + kc2 + 32 + lk);
  }
  for (int kt = 0; kt < 32; ++kt) {
    // issue V(kt+2) then K(kt+1)  (drain order at the wait: ..V(kt+1),K(kt))
    if (kt + 2 < 32) stage_v(V3[(kt + 2) % 3], kt + 2);
    if (kt + 1 < 32) {
      size_t kro = (size_t)(b * N_ + (kt + 1) * 32 + kh * 16 + lr) * DQKV;
      knxt[0] = *(const s16x8*)(qkv + kro + kc1 + lk);
      knxt[1] = *(const s16x8*)(qkv + kro + kc1 + 32 + lk);
      knxt[2] = *(const s16x8*)(qkv + kro + kc2 + lk);
      knxt[3] = *(const s16x8*)(qkv + kro + kc2 + 32 + lk);
    }
    if (kt <= 29)      WAITV(8);   // drains K(kt) [+V(kt+1)]; keeps V(kt+2),K(kt+1)
    else if (kt == 30) WAITV(4);   // queue: V31,K30,K31 -> drains V31,K30
    else               WAITV(0);   // queue: K31 -> drain
    // QK both types, kv = kt*32 + kh*16 + lr
    f32x4 t1 = __builtin_amdgcn_mfma_f32_16x16x32_bf16(q1f[0], kcur[0], zero, 0, 0, 0);
    f32x4 s1 = __builtin_amdgcn_mfma_f32_16x16x32_bf16(q1f[1], kcur[1], t1, 0, 0, 0);
    f32x4 t2 = __builtin_amdgcn_mfma_f32_16x16x32_bf16(q2f[0], kcur[2], zero, 0, 0, 0);
    f32x4 s2 = __builtin_amdgcn_mfma_f32_16x16x32_bf16(q2f[1], kcur[3], t2, 0, 0, 0);
    // P = e1/l1 - lam*e2/l2 (no-max exact softmax); stripe [rows rs*16..][kv kh*16+lr]
    unsigned short* Pt = Pb[kt & 1];
    #pragma unroll
    for (int r = 0; r < 4; ++r) {
      float p = __expf(s1[r] * scale) * r1v[r] - __expf(s2[r] * scale) * r2v[r];
      Pt[(rs * 16 + lg * 4 + r) * 36 + kh * 16 + lr] = f2bf(p);
    }
    WAITL0();                          // P ds_writes visible; vmem stays in flight
    __builtin_amdgcn_s_barrier();      // ONE barrier per iteration
    // PV: full P [64][32] x wave's private V slice [32][64ch]
    __builtin_amdgcn_s_setprio(1);
    unsigned short* Vb = V3[kt % 3];
    #pragma unroll
    for (int mf = 0; mf < 4; ++mf) {
      s16x8 pf = *(const s16x8*)&Pt[(mf * 16 + lr) * 36 + lk];
      #pragma unroll
      for (int nf = 0; nf < 4; ++nf) {
        s16x8 vfr = VREAD(Vb, nf);
        O[mf][nf] = __builtin_amdgcn_mfma_f32_16x16x32_bf16(pf, vfr, O[mf][nf], 0, 0, 0);
      }
    }
    __builtin_amdgcn_s_setprio(0);
    if (kt < 31) {
      #pragma unroll
      for (int i = 0; i < 4; ++i) kcur[i] = knxt[i];
    }
  }
#undef VREAD
  // epilogue
  #pragma unroll
  for (int mf = 0; mf < 4; ++mf)
    #pragma unroll
    for (int nf = 0; nf < 4; ++nf) {
      int col = h * 512 + w * 64 + nf * 16 + lr;
      #pragma unroll
      for (int r = 0; r < 4; ++r) {
        int row = b * N_ + qt * 64 + mf * 16 + lg * 4 + r;
        aout[(size_t)row * DQKV + col] = f2bf(O[mf][nf][r]);
      }
    }
}

// ---------------------------------- launcher ------------------------------------
extern "C" void kernel_launch(void* const* d_in, const int* in_sizes, int n_in,
                              void* d_out, int out_size, void* d_ws, size_t ws_size,
                              hipStream_t stream) {
  const float* x    = (const float*)d_in[0];
  const float* t    = (const float*)d_in[1];
  const float* ln1g = (const float*)d_in[2];
  const float* ln1b = (const float*)d_in[3];
  const float* Wqkv = (const float*)d_in[4];
  const float* bqkv = (const float*)d_in[5];
  const float* lam  = (const float*)d_in[6];
  const float* Wm   = (const float*)d_in[7];
  const float* bm   = (const float*)d_in[8];
  const float* Wt1  = (const float*)d_in[9];
  const float* bt1  = (const float*)d_in[10];
  const float* Wt2  = (const float*)d_in[11];
  const float* bt2  = (const float*)d_in[12];
  const float* lnfg = (const float*)d_in[13];
  const float* lnfb = (const float*)d_in[14];
  const float* Wf1  = (const float*)d_in[15];
  const float* bf1  = (const float*)d_in[16];
  const float* Wf2  = (const float*)d_in[17];
  const float* bf2  = (const float*)d_in[18];
  float* out = (float*)d_out;
  char* ws = (char*)d_ws;

  // workspace layout (bytes), ~209 MB total
  unsigned short* qkv   = (unsigned short*)(ws);                  // [8192][6144] bf16 (100.7MB)
  unsigned short* vt    = (unsigned short*)(ws + 100663296ull);   // [64][512][1024] bf16 (67MB)
  float*          x2    = (float*)(ws + 167772160ull);            // [8192][512] f32 (16.8MB)
  unsigned short* xn    = (unsigned short*)(ws + 184549376ull);   // [8192][512] bf16 (xn, then h)
  unsigned short* WqkvT = (unsigned short*)(ws + 193986560ull);   // [6144][512]
  unsigned short* WmT   = (unsigned short*)(ws + 200278016ull);   // [512][4096]
  unsigned short* Wf1T  = (unsigned short*)(ws + 204472320ull);   // [2048][512]
  unsigned short* Wf2T  = (unsigned short*)(ws + 206569472ull);   // [512][2048]
  float*          tp    = (float*)(ws + 208666624ull);            // [8][512]
  unsigned short* ff1s  = qkv;          // alias: qkv dead after attention
  unsigned short* aout  = qkv + 2048;   // alias: attention out over dead V region

  // weights -> bf16 transposed [N][K]
  wtrans_k<<<dim3(DQKV / 32, DIN / 32),  256, 0, stream>>>(Wqkv, WqkvT, DIN, DQKV);
  wtrans_k<<<dim3(DIN / 32, 4096 / 32),  256, 0, stream>>>(Wm,   WmT,   4096, DIN);
  wtrans_k<<<dim3(DEXP / 32, DIN / 32),  256, 0, stream>>>(Wf1,  Wf1T,  DIN, DEXP);
  wtrans_k<<<dim3(DIN / 32, DEXP / 32),  256, 0, stream>>>(Wf2,  Wf2T,  DEXP, DIN);
  // ln1 + time MLP
  ln_k<<<8192, 256, 0, stream>>>(x, nullptr, ln1g, ln1b, xn);
  time_k<<<8, 256, 0, stream>>>(t, Wt1, bt1, Wt2, bt2, tp);
  // qkv GEMM (V columns written directly transposed into vt)
  gemm_bt<3><<<dim3(DQKV / 128, 8192 / 128), 256, 0, stream>>>(
      xn, DIN, WqkvT, bqkv, nullptr, qkv, DQKV, DQKV, DIN, vt);
  // fused two-pass differential attention (reg-K prefetch + private V3 pipeline)
  attn_k<<<1024, 512, 0, stream>>>(qkv, vt, lam, aout);
  // x2 = x + attn_out @ Wm + bm
  gemm_bt<2><<<dim3(DIN / 128, 8192 / 128), 256, 0, stream>>>(
      aout, DQKV, WmT, bm, x, x2, DIN, DIN, 4096, nullptr);
  // h = LN(x2 + tp)
  ln_k<<<8192, 256, 0, stream>>>(x2, tp, lnfg, lnfb, xn);
  // ff1 = swish(h @ Wf1 + bf1)
  gemm_bt<1><<<dim3(DEXP / 128, 8192 / 128), 256, 0, stream>>>(
      xn, DIN, Wf1T, bf1, nullptr, ff1s, DEXP, DEXP, DIN, nullptr);
  // out = x2 + ff1 @ Wf2 + bf2
  gemm_bt<2><<<dim3(DIN / 128, 8192 / 128), 256, 0, stream>>>(
      ff1s, DEXP, Wf2T, bf2, x2, out, DIN, DIN, DEXP, nullptr);
}